// Round 1
// baseline (1165.345 us; speedup 1.0000x reference)
//
#include <hip/hip_runtime.h>
#include <math.h>

#define NRAYS_EXPECTED 2048
#define SAMPLES 64
#define HIDDEN 256
#define PE_FREQS 10
#define IN_PE 63            // 3 + 3*2*10

// LDS layout (floats):
//   bufA: 16384 floats (HIDDEN x 64 points, float4-grouped over k)
//   bufB: 16384 floats (same shape)
//   pe  : aliases bufB (63*64 floats), consumed only in layer 0
// total dynamic LDS = 131072 bytes -> 1 block/CU (160 KiB available)

__device__ __forceinline__ void dense256_relu(const float* __restrict__ W,
                                              const float* __restrict__ b,
                                              const float* __restrict__ inBuf,
                                              float* __restrict__ outBuf,
                                              int j0, int lane)
{
    float acc[64];
#pragma unroll
    for (int jj = 0; jj < 64; ++jj) acc[jj] = b[j0 + jj];

    const float4* in4 = (const float4*)inBuf;
    for (int kg = 0; kg < 64; ++kg) {
        float4 h4 = in4[kg * 64 + lane];                 // k = 4*kg .. 4*kg+3 for this lane's point
        const float* wr = W + kg * 4 * HIDDEN + j0;      // wave-uniform -> s_load
#pragma unroll
        for (int jj = 0; jj < 64; ++jj) acc[jj] = fmaf(wr[jj],            h4.x, acc[jj]);
#pragma unroll
        for (int jj = 0; jj < 64; ++jj) acc[jj] = fmaf(wr[HIDDEN + jj],   h4.y, acc[jj]);
#pragma unroll
        for (int jj = 0; jj < 64; ++jj) acc[jj] = fmaf(wr[2*HIDDEN + jj], h4.z, acc[jj]);
#pragma unroll
        for (int jj = 0; jj < 64; ++jj) acc[jj] = fmaf(wr[3*HIDDEN + jj], h4.w, acc[jj]);
    }

    float4* out4 = (float4*)outBuf;
#pragma unroll
    for (int g = 0; g < 16; ++g) {
        float4 v;
        v.x = fmaxf(acc[4*g + 0], 0.0f);
        v.y = fmaxf(acc[4*g + 1], 0.0f);
        v.z = fmaxf(acc[4*g + 2], 0.0f);
        v.w = fmaxf(acc[4*g + 3], 0.0f);
        out4[((j0 >> 2) + g) * 64 + lane] = v;
    }
}

__launch_bounds__(256, 1)
__global__ void nerf_fused(const float* __restrict__ origins,
                           const float* __restrict__ dirs,
                           const float* __restrict__ nearp,
                           const float* __restrict__ farp,
                           const float* __restrict__ W0, const float* __restrict__ b0,
                           const float* __restrict__ W1, const float* __restrict__ b1,
                           const float* __restrict__ W2, const float* __restrict__ b2,
                           const float* __restrict__ W3, const float* __restrict__ b3,
                           float* __restrict__ out)
{
    extern __shared__ float sm[];
    float* bufA = sm;                // 16384 floats
    float* bufB = sm + 16384;        // 16384 floats
    float* pe   = bufB;              // alias: dead once layer 0 has read it

    const int tid  = threadIdx.x;
    const int wv   = tid >> 6;
    const int lane = tid & 63;
    const int ray  = blockIdx.x;

    const float near = nearp[0];
    const float far  = farp[0];
    const float step = (far - near) * (1.0f / 64.0f);

    const float ox = origins[ray*3+0], oy = origins[ray*3+1], oz = origins[ray*3+2];
    const float dx = dirs[ray*3+0],    dy = dirs[ray*3+1],    dz = dirs[ray*3+2];

    // ---- phase 0: positional encoding -> pe[k*64 + p], k in [0,63)
    for (int idx = tid; idx < IN_PE * SAMPLES; idx += 256) {
        int k = idx >> 6;
        int p = idx & 63;
        // reference midpoint formula: b[p] + b[p+1]/2
        float m = (near + (float)p * step) + (near + (float)(p + 1) * step) * 0.5f;
        float lx = ox + m * dx, ly = oy + m * dy, lz = oz + m * dz;
        float v;
        if (k < 3) {
            v = (k == 0) ? lx : ((k == 1) ? ly : lz);
        } else {
            int t = k - 3;
            int l = t / 6, r = t % 6;
            int d = r % 3;
            float base = (d == 0) ? lx : ((d == 1) ? ly : lz);
            float a = base * (float)(1 << l);
            v = (r < 3) ? sinf(a) : cosf(a);
        }
        pe[k * 64 + p] = v;
    }
    __syncthreads();

    // wave-uniform output-channel base (forces SGPR addressing for weights)
    const int j0 = __builtin_amdgcn_readfirstlane(wv << 6);

    // ---- layer 0: pe(63) -> bufA(256), relu
    {
        float acc[64];
#pragma unroll
        for (int jj = 0; jj < 64; ++jj) acc[jj] = b0[j0 + jj];
        for (int k = 0; k < IN_PE; ++k) {
            float h = pe[k * 64 + lane];
            const float* wr = W0 + k * HIDDEN + j0;
#pragma unroll
            for (int jj = 0; jj < 64; ++jj) acc[jj] = fmaf(wr[jj], h, acc[jj]);
        }
        float4* out4 = (float4*)bufA;
#pragma unroll
        for (int g = 0; g < 16; ++g) {
            float4 v;
            v.x = fmaxf(acc[4*g + 0], 0.0f);
            v.y = fmaxf(acc[4*g + 1], 0.0f);
            v.z = fmaxf(acc[4*g + 2], 0.0f);
            v.w = fmaxf(acc[4*g + 3], 0.0f);
            out4[((j0 >> 2) + g) * 64 + lane] = v;
        }
    }
    __syncthreads();

    // ---- layer 1: bufA -> bufB (this overwrites the dead pe alias)
    dense256_relu(W1, b1, bufA, bufB, j0, lane);
    __syncthreads();

    // ---- layer 2: bufB -> bufA
    dense256_relu(W2, b2, bufB, bufA, j0, lane);
    __syncthreads();

    // ---- layer 3 (256 -> 4) + compositing: wave 0 only, lane = sample
    if (wv == 0) {
        float f[4] = { b3[0], b3[1], b3[2], b3[3] };
        const float4* in4 = (const float4*)bufA;
        for (int kg = 0; kg < 64; ++kg) {
            float4 h4 = in4[kg * 64 + lane];
            const float* wr = W3 + kg * 16;   // rows 4kg..4kg+3, 4 cols each
#pragma unroll
            for (int jj = 0; jj < 4; ++jj) f[jj] = fmaf(wr[jj],      h4.x, f[jj]);
#pragma unroll
            for (int jj = 0; jj < 4; ++jj) f[jj] = fmaf(wr[4 + jj],  h4.y, f[jj]);
#pragma unroll
            for (int jj = 0; jj < 4; ++jj) f[jj] = fmaf(wr[8 + jj],  h4.z, f[jj]);
#pragma unroll
            for (int jj = 0; jj < 4; ++jj) f[jj] = fmaf(wr[12 + jj], h4.w, f[jj]);
        }

        const int p = lane;
        float sigma = fmaxf(f[3], 0.0f);
        float bprev = near + (float)p * step;
        float bnext = near + (float)(p + 1) * step;
        float delta = bnext - bprev;
        float alpha = 1.0f - expf(-sigma * delta);
        float om    = 1.0f - alpha;

        // inclusive prefix product of (1-alpha) across 64 lanes
        float prod = om;
#pragma unroll
        for (int off = 1; off < 64; off <<= 1) {
            float v = __shfl_up(prod, off, 64);
            if (p >= off) prod *= v;
        }
        // exclusive transmittance
        float T = __shfl_up(prod, 1, 64);
        if (p == 0) T = 1.0f;
        float w = T * alpha;

        float r = w * (1.0f / (1.0f + expf(-f[0])));
        float g = w * (1.0f / (1.0f + expf(-f[1])));
        float bl = w * (1.0f / (1.0f + expf(-f[2])));
#pragma unroll
        for (int off = 32; off > 0; off >>= 1) {
            r  += __shfl_down(r,  off, 64);
            g  += __shfl_down(g,  off, 64);
            bl += __shfl_down(bl, off, 64);
        }
        if (p == 0) {
            out[ray*3 + 0] = r;
            out[ray*3 + 1] = g;
            out[ray*3 + 2] = bl;
        }
    }
}

extern "C" void kernel_launch(void* const* d_in, const int* in_sizes, int n_in,
                              void* d_out, int out_size, void* d_ws, size_t ws_size,
                              hipStream_t stream) {
    const float* origins = (const float*)d_in[0];
    const float* dirs    = (const float*)d_in[1];
    const float* nearp   = (const float*)d_in[2];
    const float* farp    = (const float*)d_in[3];
    const float* W0      = (const float*)d_in[4];
    const float* b0      = (const float*)d_in[5];
    const float* W1      = (const float*)d_in[6];
    const float* b1      = (const float*)d_in[7];
    const float* W2      = (const float*)d_in[8];
    const float* b2      = (const float*)d_in[9];
    const float* W3      = (const float*)d_in[10];
    const float* b3      = (const float*)d_in[11];
    float* out           = (float*)d_out;

    const int nrays = in_sizes[0] / 3;
    const size_t shmem = 2 * 16384 * sizeof(float);   // 128 KiB

    hipFuncSetAttribute(reinterpret_cast<const void*>(nerf_fused),
                        hipFuncAttributeMaxDynamicSharedMemorySize,
                        (int)shmem);

    nerf_fused<<<dim3(nrays), dim3(256), shmem, stream>>>(
        origins, dirs, nearp, farp,
        W0, b0, W1, b1, W2, b2, W3, b3, out);
}

// Round 2
// 745.149 us; speedup vs baseline: 1.5639x; 1.5639x over previous
//
#include <hip/hip_runtime.h>
#include <math.h>

#define SAMPLES 64
#define HIDDEN 256
#define PE_FREQS 10
#define IN_PE 63            // 3 + 3*2*10

// LDS layout (floats):
//   act: 16384 floats (HIDDEN x 64 points, float4-grouped over k) = 64 KB
//   pe : 63*64 floats = 15.75 KB  (reused as head-partial scratch later)
// total dynamic LDS = 81664 B = 79.75 KB -> 2 blocks/CU (159.5 KB of 160 KB)

// In-place dense 256->256 + relu. Safe because every wave reads ALL of buf
// before the barrier, and writes only after it.
__device__ __forceinline__ void dense256_relu_inplace(const float* __restrict__ W,
                                                      const float* __restrict__ b,
                                                      float* buf,
                                                      int j0, int lane)
{
    float acc[64];
#pragma unroll
    for (int jj = 0; jj < 64; ++jj) acc[jj] = b[j0 + jj];

    const float4* in4 = (const float4*)buf;
    float4 h4 = in4[lane];                               // kg = 0 prefetch
    for (int kg = 0; kg < 64; ++kg) {
        float4 h4n = in4[(((kg + 1) & 63) * 64) + lane]; // prefetch next (wraps harmlessly)
        const float* wr = W + kg * 4 * HIDDEN + j0;      // wave-uniform -> s_load
#pragma unroll
        for (int jj = 0; jj < 64; ++jj) acc[jj] = fmaf(wr[jj],            h4.x, acc[jj]);
#pragma unroll
        for (int jj = 0; jj < 64; ++jj) acc[jj] = fmaf(wr[HIDDEN + jj],   h4.y, acc[jj]);
#pragma unroll
        for (int jj = 0; jj < 64; ++jj) acc[jj] = fmaf(wr[2*HIDDEN + jj], h4.z, acc[jj]);
#pragma unroll
        for (int jj = 0; jj < 64; ++jj) acc[jj] = fmaf(wr[3*HIDDEN + jj], h4.w, acc[jj]);
        h4 = h4n;
    }

    __syncthreads();   // all reads done everywhere before any write

    float4* out4 = (float4*)buf;
#pragma unroll
    for (int g = 0; g < 16; ++g) {
        float4 v;
        v.x = fmaxf(acc[4*g + 0], 0.0f);
        v.y = fmaxf(acc[4*g + 1], 0.0f);
        v.z = fmaxf(acc[4*g + 2], 0.0f);
        v.w = fmaxf(acc[4*g + 3], 0.0f);
        out4[((j0 >> 2) + g) * 64 + lane] = v;
    }
    __syncthreads();
}

__launch_bounds__(256, 2)
__global__ void nerf_fused(const float* __restrict__ origins,
                           const float* __restrict__ dirs,
                           const float* __restrict__ nearp,
                           const float* __restrict__ farp,
                           const float* __restrict__ W0, const float* __restrict__ b0,
                           const float* __restrict__ W1, const float* __restrict__ b1,
                           const float* __restrict__ W2, const float* __restrict__ b2,
                           const float* __restrict__ W3, const float* __restrict__ b3,
                           float* __restrict__ out)
{
    extern __shared__ float sm[];
    float* act = sm;                 // 16384 floats
    float* pe  = sm + 16384;         // 4032 floats; later reused as head scratch

    const int tid  = threadIdx.x;
    const int wv   = tid >> 6;
    const int lane = tid & 63;
    const int ray  = blockIdx.x;

    const float near = nearp[0];
    const float far  = farp[0];
    const float step = (far - near) * (1.0f / 64.0f);

    const float ox = origins[ray*3+0], oy = origins[ray*3+1], oz = origins[ray*3+2];
    const float dx = dirs[ray*3+0],    dy = dirs[ray*3+1],    dz = dirs[ray*3+2];

    // ---- phase 0: positional encoding -> pe[k*64 + p], k in [0,63)
    for (int idx = tid; idx < IN_PE * SAMPLES; idx += 256) {
        int k = idx >> 6;
        int p = idx & 63;
        // reference midpoint formula: b[p] + b[p+1]/2
        float m = (near + (float)p * step) + (near + (float)(p + 1) * step) * 0.5f;
        float lx = ox + m * dx, ly = oy + m * dy, lz = oz + m * dz;
        float v;
        if (k < 3) {
            v = (k == 0) ? lx : ((k == 1) ? ly : lz);
        } else {
            int t = k - 3;
            int l = t / 6, r = t % 6;
            int d = r % 3;
            float base = (d == 0) ? lx : ((d == 1) ? ly : lz);
            float a = base * (float)(1 << l);
            v = (r < 3) ? sinf(a) : cosf(a);
        }
        pe[k * 64 + p] = v;
    }
    __syncthreads();

    // wave-uniform output-channel base (forces SGPR addressing for weights)
    const int j0 = __builtin_amdgcn_readfirstlane(wv << 6);

    // ---- layer 0: pe(63) -> act(256), relu   (pe/act disjoint; no in-place hazard)
    {
        float acc[64];
#pragma unroll
        for (int jj = 0; jj < 64; ++jj) acc[jj] = b0[j0 + jj];
        for (int k = 0; k < IN_PE; ++k) {
            float h = pe[k * 64 + lane];
            const float* wr = W0 + k * HIDDEN + j0;
#pragma unroll
            for (int jj = 0; jj < 64; ++jj) acc[jj] = fmaf(wr[jj], h, acc[jj]);
        }
        float4* out4 = (float4*)act;
#pragma unroll
        for (int g = 0; g < 16; ++g) {
            float4 v;
            v.x = fmaxf(acc[4*g + 0], 0.0f);
            v.y = fmaxf(acc[4*g + 1], 0.0f);
            v.z = fmaxf(acc[4*g + 2], 0.0f);
            v.w = fmaxf(acc[4*g + 3], 0.0f);
            out4[((j0 >> 2) + g) * 64 + lane] = v;
        }
    }
    __syncthreads();

    // ---- layers 1,2: in-place
    dense256_relu_inplace(W1, b1, act, j0, lane);
    dense256_relu_inplace(W2, b2, act, j0, lane);

    // ---- layer 3 (256 -> 4): k-split across 4 waves, partials into pe scratch
    {
        float f0 = 0.f, f1 = 0.f, f2 = 0.f, f3 = 0.f;
        if (wv == 0) { f0 = b3[0]; f1 = b3[1]; f2 = b3[2]; f3 = b3[3]; }
        const float4* in4 = (const float4*)act;
        const int kg0 = wv * 16;
        for (int kg = kg0; kg < kg0 + 16; ++kg) {
            float4 h4 = in4[kg * 64 + lane];
            const float* wr = W3 + kg * 16;   // rows 4kg..4kg+3, 4 cols each
            f0 = fmaf(wr[0],  h4.x, f0); f1 = fmaf(wr[1],  h4.x, f1);
            f2 = fmaf(wr[2],  h4.x, f2); f3 = fmaf(wr[3],  h4.x, f3);
            f0 = fmaf(wr[4],  h4.y, f0); f1 = fmaf(wr[5],  h4.y, f1);
            f2 = fmaf(wr[6],  h4.y, f2); f3 = fmaf(wr[7],  h4.y, f3);
            f0 = fmaf(wr[8],  h4.z, f0); f1 = fmaf(wr[9],  h4.z, f1);
            f2 = fmaf(wr[10], h4.z, f2); f3 = fmaf(wr[11], h4.z, f3);
            f0 = fmaf(wr[12], h4.w, f0); f1 = fmaf(wr[13], h4.w, f1);
            f2 = fmaf(wr[14], h4.w, f2); f3 = fmaf(wr[15], h4.w, f3);
        }
        float4* part4 = (float4*)pe;          // pe region is dead now
        part4[wv * 64 + lane] = make_float4(f0, f1, f2, f3);
    }
    __syncthreads();

    // ---- compositing: wave 0, lane = sample
    if (wv == 0) {
        const float4* part4 = (const float4*)pe;
        float4 a0 = part4[lane], a1 = part4[64 + lane],
               a2 = part4[128 + lane], a3 = part4[192 + lane];
        float f[4] = { a0.x + a1.x + a2.x + a3.x,
                       a0.y + a1.y + a2.y + a3.y,
                       a0.z + a1.z + a2.z + a3.z,
                       a0.w + a1.w + a2.w + a3.w };

        const int p = lane;
        float sigma = fmaxf(f[3], 0.0f);
        float delta = (near + (float)(p + 1) * step) - (near + (float)p * step);
        float alpha = 1.0f - expf(-sigma * delta);
        float om    = 1.0f - alpha;

        // inclusive prefix product of (1-alpha) across 64 lanes
        float prod = om;
#pragma unroll
        for (int off = 1; off < 64; off <<= 1) {
            float v = __shfl_up(prod, off, 64);
            if (p >= off) prod *= v;
        }
        float T = __shfl_up(prod, 1, 64);
        if (p == 0) T = 1.0f;
        float w = T * alpha;

        float r  = w * (1.0f / (1.0f + expf(-f[0])));
        float g  = w * (1.0f / (1.0f + expf(-f[1])));
        float bl = w * (1.0f / (1.0f + expf(-f[2])));
#pragma unroll
        for (int off = 32; off > 0; off >>= 1) {
            r  += __shfl_down(r,  off, 64);
            g  += __shfl_down(g,  off, 64);
            bl += __shfl_down(bl, off, 64);
        }
        if (p == 0) {
            out[ray*3 + 0] = r;
            out[ray*3 + 1] = g;
            out[ray*3 + 2] = bl;
        }
    }
}

extern "C" void kernel_launch(void* const* d_in, const int* in_sizes, int n_in,
                              void* d_out, int out_size, void* d_ws, size_t ws_size,
                              hipStream_t stream) {
    const float* origins = (const float*)d_in[0];
    const float* dirs    = (const float*)d_in[1];
    const float* nearp   = (const float*)d_in[2];
    const float* farp    = (const float*)d_in[3];
    const float* W0      = (const float*)d_in[4];
    const float* b0      = (const float*)d_in[5];
    const float* W1      = (const float*)d_in[6];
    const float* b1      = (const float*)d_in[7];
    const float* W2      = (const float*)d_in[8];
    const float* b2      = (const float*)d_in[9];
    const float* W3      = (const float*)d_in[10];
    const float* b3      = (const float*)d_in[11];
    float* out           = (float*)d_out;

    const int nrays = in_sizes[0] / 3;
    const size_t shmem = (16384 + IN_PE * SAMPLES) * sizeof(float);  // 81664 B

    hipFuncSetAttribute(reinterpret_cast<const void*>(nerf_fused),
                        hipFuncAttributeMaxDynamicSharedMemorySize,
                        (int)shmem);

    nerf_fused<<<dim3(nrays), dim3(256), shmem, stream>>>(
        origins, dirs, nearp, farp,
        W0, b0, W1, b1, W2, b2, W3, b3, out);
}

// Round 3
// 189.602 us; speedup vs baseline: 6.1463x; 3.9301x over previous
//
#include <hip/hip_runtime.h>
#include <math.h>

typedef _Float16 h8 __attribute__((ext_vector_type(8)));
typedef float    f4 __attribute__((ext_vector_type(4)));

#define SAMPLES 64
#define HIDDEN  256
#define IN_PE   63

// d_ws layout (units: _Float16). Weights pre-split hi/lo, pre-swizzled into
// MFMA B-fragment order [kg][nt][lane][8] so each lane loads 16 B contiguous.
#define OFF_W0HI 0            // [2][16][64][8]  = 16384
#define OFF_W0LO 16384
#define OFF_W1HI 32768        // [8][16][64][8]  = 65536
#define OFF_W1LO 98304
#define OFF_W2HI 163840
#define OFF_W2LO 229376
#define OFF_W3HI 294912       // [8][1][64][8]   = 4096 (W3 zero-padded 4->16 cols)
#define OFF_W3LO 299008
// total 303104 halfs = 606208 bytes of ws

__global__ void prep_weights(const float* __restrict__ W0,
                             const float* __restrict__ W1,
                             const float* __restrict__ W2,
                             const float* __restrict__ W3,
                             _Float16* __restrict__ ws)
{
    int id = blockIdx.x * blockDim.x + threadIdx.x;   // one thread per 8-elem dest block
    const int NB0 = 2*16*64;     // 2048
    const int NB1 = 8*16*64;     // 8192
    const int NB3 = 8*64;        // 512
    if (id >= NB0 + 2*NB1 + NB3) return;

    const float* src; _Float16 *hi, *lo;
    int b, kg, nt, fl, fanout, kmax;
    if (id < NB0)            { b=id;           src=W0; hi=ws+OFF_W0HI; lo=ws+OFF_W0LO; fanout=256; kmax=63;  kg=b>>10; nt=(b>>6)&15; fl=b&63; }
    else if (id < NB0+NB1)   { b=id-NB0;       src=W1; hi=ws+OFF_W1HI; lo=ws+OFF_W1LO; fanout=256; kmax=256; kg=b>>10; nt=(b>>6)&15; fl=b&63; }
    else if (id < NB0+2*NB1) { b=id-NB0-NB1;   src=W2; hi=ws+OFF_W2HI; lo=ws+OFF_W2LO; fanout=256; kmax=256; kg=b>>10; nt=(b>>6)&15; fl=b&63; }
    else                     { b=id-NB0-2*NB1; src=W3; hi=ws+OFF_W3HI; lo=ws+OFF_W3LO; fanout=4;   kmax=256; kg=b>>6;  nt=0;        fl=b&63; }

    int col = nt*16 + (fl & 15);                 // B-frag: n = lane&15
    int k0  = kg*32 + ((fl >> 4) << 3);          // B-frag: k = (lane>>4)*8 + j
    h8 vh, vl;
#pragma unroll
    for (int j = 0; j < 8; ++j) {
        int k = k0 + j;
        float v = 0.0f;
        if (k < kmax && col < fanout) v = src[k*fanout + col];
        _Float16 h = (_Float16)v;
        vh[j] = h;
        vl[j] = (_Float16)(v - (float)h);
    }
    ((h8*)hi)[b] = vh;
    ((h8*)lo)[b] = vl;
}

__device__ __forceinline__ f4 mfma3(h8 ahi, h8 alo, h8 bhi, h8 blo, f4 c)
{
    c = __builtin_amdgcn_mfma_f32_16x16x32_f16(alo, bhi, c, 0, 0, 0);
    c = __builtin_amdgcn_mfma_f32_16x16x32_f16(ahi, blo, c, 0, 0, 0);
    c = __builtin_amdgcn_mfma_f32_16x16x32_f16(ahi, bhi, c, 0, 0, 0);
    return c;
}

// One dense layer: H[64][K] (LDS, A-frag layout, hi/lo f16) @ W[K][256] -> relu
// -> write back in-place into A-frag layout (K'=256 for the next layer).
template<int NKG>
__device__ __forceinline__ void dense_layer(const _Float16* __restrict__ Whi,
                                            const _Float16* __restrict__ Wlo,
                                            const float*    __restrict__ bias,
                                            _Float16* Ahi, _Float16* Alo,
                                            int wv, int lane)
{
    const int q  = lane >> 4;
    const int jl = lane & 15;
    f4 acc[4][4];
#pragma unroll
    for (int nt = 0; nt < 4; ++nt) {
        float bj = bias[wv*64 + nt*16 + jl];     // C col = lane&15
#pragma unroll
        for (int mt = 0; mt < 4; ++mt) acc[mt][nt] = (f4){bj, bj, bj, bj};
    }

    const h8* ah = (const h8*)Ahi;
    const h8* al = (const h8*)Alo;
    const h8* wh = (const h8*)Whi;
    const h8* wl = (const h8*)Wlo;

    for (int kg = 0; kg < NKG; ++kg) {
        h8 bh[4], bl[4], af[4], af2[4];
#pragma unroll
        for (int nt = 0; nt < 4; ++nt) {
            int wi = (kg*16 + wv*4 + nt)*64 + lane;     // coalesced 16 B/lane, L2-hot
            bh[nt] = wh[wi];
            bl[nt] = wl[wi];
        }
#pragma unroll
        for (int mt = 0; mt < 4; ++mt) {
            int ai = (kg*4 + mt)*64 + lane;             // ds_read_b128, conflict-free
            af[mt]  = ah[ai];
            af2[mt] = al[ai];
        }
#pragma unroll
        for (int mt = 0; mt < 4; ++mt)
#pragma unroll
            for (int nt = 0; nt < 4; ++nt)
                acc[mt][nt] = mfma3(af[mt], af2[mt], bh[nt], bl[nt], acc[mt][nt]);
    }

    __syncthreads();   // all waves done reading H before in-place overwrite

    // relu + fp16 split + scatter into A-frag layout for the next layer
#pragma unroll
    for (int nt = 0; nt < 4; ++nt) {
        int k   = wv*64 + nt*16 + jl;    // this output channel = next layer's k
        int kgd = (k >> 5) * 4;
        int sub = (k >> 3) & 3;
        int jj  = k & 7;
#pragma unroll
        for (int mt = 0; mt < 4; ++mt) {
#pragma unroll
            for (int r = 0; r < 4; ++r) {
                float v = fmaxf(acc[mt][nt][r], 0.0f);
                _Float16 h = (_Float16)v;
                _Float16 l = (_Float16)(v - (float)h);
                int mm  = q*4 + r;                        // m&15  (m = mt*16 + mm)
                int idx = ((kgd + mt)*64 + (mm | (sub<<4)))*8 + jj;
                Ahi[idx] = h;
                Alo[idx] = l;
            }
        }
    }
    __syncthreads();
}

__launch_bounds__(256, 2)
__global__ void nerf_fused(const float* __restrict__ origins,
                           const float* __restrict__ dirs,
                           const float* __restrict__ nearp,
                           const float* __restrict__ farp,
                           const float* __restrict__ b0,
                           const float* __restrict__ b1,
                           const float* __restrict__ b2,
                           const float* __restrict__ b3,
                           const _Float16* __restrict__ ws,
                           float* __restrict__ out)
{
    extern __shared__ _Float16 sm[];
    _Float16* Ahi = sm;            // [8kg][4mt][64lane][8] f16 = 32 KB
    _Float16* Alo = sm + 16384;    // 32 KB                (total 64 KB -> 2 blocks/CU)

    const int tid  = threadIdx.x;
    const int wv   = tid >> 6;
    const int lane = tid & 63;
    const int ray  = blockIdx.x;

    const float near = nearp[0];
    const float far  = farp[0];
    const float step = (far - near) * (1.0f / 64.0f);

    const float ox = origins[ray*3+0], oy = origins[ray*3+1], oz = origins[ray*3+2];
    const float dx = dirs[ray*3+0],    dy = dirs[ray*3+1],    dz = dirs[ray*3+2];

    // ---- PE directly into A-frag layout (K padded 63->64, kg = 0..1)
#pragma unroll
    for (int i = 0; i < 2; ++i) {
        int b  = tid + i*256;            // 0..511 = [kg 0..1][mt 0..3][fl 0..63]
        int kg = b >> 8;
        int mt = (b >> 6) & 3;
        int fl = b & 63;
        int m  = mt*16 + (fl & 15);
        int k0 = kg*32 + ((fl >> 4) << 3);
        float mid = (near + (float)m*step) + (near + (float)(m+1)*step)*0.5f;  // ref formula
        float c3[3] = { ox + mid*dx, oy + mid*dy, oz + mid*dz };
        h8 vh, vl;
#pragma unroll
        for (int j = 0; j < 8; ++j) {
            int k = k0 + j;
            float v;
            if (k < 3) v = c3[k];
            else if (k < 63) {
                int t = k - 3, l = t/6, r = t%6, d = r%3;
                float a = c3[d] * (float)(1 << l);
                v = (r < 3) ? sinf(a) : cosf(a);
            } else v = 0.0f;
            _Float16 h = (_Float16)v;
            vh[j] = h;
            vl[j] = (_Float16)(v - (float)h);
        }
        ((h8*)Ahi)[b] = vh;
        ((h8*)Alo)[b] = vl;
    }
    __syncthreads();

    dense_layer<2>(ws+OFF_W0HI, ws+OFF_W0LO, b0, Ahi, Alo, wv, lane);
    dense_layer<8>(ws+OFF_W1HI, ws+OFF_W1LO, b1, Ahi, Alo, wv, lane);
    dense_layer<8>(ws+OFF_W2HI, ws+OFF_W2LO, b2, Ahi, Alo, wv, lane);

    // ---- head: [64x256] @ W3pad[256x16], K-split across waves (2 kg each)
    const int q  = lane >> 4;
    const int jl = lane & 15;
    f4 hacc[4];
    float binit = (wv == 0 && jl < 4) ? b3[jl] : 0.0f;
#pragma unroll
    for (int mt = 0; mt < 4; ++mt) hacc[mt] = (f4){binit, binit, binit, binit};
    {
        const h8* ah = (const h8*)Ahi;
        const h8* al = (const h8*)Alo;
        const h8* wh = (const h8*)(ws+OFF_W3HI);
        const h8* wl = (const h8*)(ws+OFF_W3LO);
#pragma unroll
        for (int kk = 0; kk < 2; ++kk) {
            int kg = wv*2 + kk;
            h8 bh = wh[kg*64 + lane];
            h8 bl = wl[kg*64 + lane];
#pragma unroll
            for (int mt = 0; mt < 4; ++mt) {
                int ai = (kg*4 + mt)*64 + lane;
                hacc[mt] = mfma3(ah[ai], al[ai], bh, bl, hacc[mt]);
            }
        }
    }
    __syncthreads();                       // A reads done everywhere -> safe to alias

    float* part  = (float*)sm;             // [wv][mt][lane] f4 = 16 KB (aliases Ahi)
    float* headv = (float*)(sm + 16384);   // [m][4] f32 = 1 KB (aliases Alo)
    f4* partv = (f4*)part;
#pragma unroll
    for (int mt = 0; mt < 4; ++mt) partv[(wv*4 + mt)*64 + lane] = hacc[mt];
    __syncthreads();

    if (wv == 0) {
#pragma unroll
        for (int mt = 0; mt < 4; ++mt) {
            f4 s = partv[(0  + mt)*64 + lane];
            s   += partv[(4  + mt)*64 + lane];
            s   += partv[(8  + mt)*64 + lane];
            s   += partv[(12 + mt)*64 + lane];
            if (jl < 4) {
#pragma unroll
                for (int r = 0; r < 4; ++r)
                    headv[(mt*16 + q*4 + r)*4 + jl] = s[r];   // C row = q*4+r
            }
        }
    }
    __syncthreads();

    // ---- compositing: wave 0, lane = sample
    if (wv == 0) {
        float4 f = ((const float4*)headv)[lane];   // x,y,z = rgb logits, w = sigma
        const int p = lane;
        float sigma = fmaxf(f.w, 0.0f);
        float delta = (near + (float)(p + 1)*step) - (near + (float)p*step);
        float alpha = 1.0f - expf(-sigma * delta);
        float om    = 1.0f - alpha;

        float prod = om;
#pragma unroll
        for (int off = 1; off < 64; off <<= 1) {
            float v = __shfl_up(prod, off, 64);
            if (p >= off) prod *= v;
        }
        float T = __shfl_up(prod, 1, 64);
        if (p == 0) T = 1.0f;
        float w = T * alpha;

        float r  = w * (1.0f / (1.0f + expf(-f.x)));
        float g  = w * (1.0f / (1.0f + expf(-f.y)));
        float bb = w * (1.0f / (1.0f + expf(-f.z)));
#pragma unroll
        for (int off = 32; off > 0; off >>= 1) {
            r  += __shfl_down(r,  off, 64);
            g  += __shfl_down(g,  off, 64);
            bb += __shfl_down(bb, off, 64);
        }
        if (p == 0) {
            out[ray*3 + 0] = r;
            out[ray*3 + 1] = g;
            out[ray*3 + 2] = bb;
        }
    }
}

extern "C" void kernel_launch(void* const* d_in, const int* in_sizes, int n_in,
                              void* d_out, int out_size, void* d_ws, size_t ws_size,
                              hipStream_t stream) {
    const float* origins = (const float*)d_in[0];
    const float* dirs    = (const float*)d_in[1];
    const float* nearp   = (const float*)d_in[2];
    const float* farp    = (const float*)d_in[3];
    const float* W0      = (const float*)d_in[4];
    const float* b0      = (const float*)d_in[5];
    const float* W1      = (const float*)d_in[6];
    const float* b1      = (const float*)d_in[7];
    const float* W2      = (const float*)d_in[8];
    const float* b2      = (const float*)d_in[9];
    const float* W3      = (const float*)d_in[10];
    const float* b3      = (const float*)d_in[11];
    float* out           = (float*)d_out;
    _Float16* ws         = (_Float16*)d_ws;

    const int nrays = in_sizes[0] / 3;

    // weight prep: 18944 dest blocks of 8 halfs
    prep_weights<<<dim3(74), dim3(256), 0, stream>>>(W0, W1, W2, W3, ws);

    const size_t shmem = 32768 * sizeof(_Float16);   // 64 KiB
    hipFuncSetAttribute(reinterpret_cast<const void*>(nerf_fused),
                        hipFuncAttributeMaxDynamicSharedMemorySize,
                        (int)shmem);
    nerf_fused<<<dim3(nrays), dim3(256), shmem, stream>>>(
        origins, dirs, nearp, farp, b0, b1, b2, b3, ws, out);
}